// Round 4
// baseline (210.846 us; speedup 1.0000x reference)
//
#include <hip/hip_runtime.h>
#include <hip/hip_bf16.h>

// CRF loss via associative chunked scan (MFMA layouts verified R2/R3).
// R4: launch_bounds(256,4) to keep MFMA operands in arch VGPRs (kill accvgpr
// round-trips), 2-deep prefetch for feat/label/gold loads, rescale every 16,
// paired f32x2 muls in the A-build.

constexpr int BN = 1024, TN = 1024, LN = 32;
constexpr float KSHIFT = 8.5f;     // per-step factors ~e^{-2}: monotone decay
constexpr float LN2F   = 0.69314718056f;

typedef __attribute__((ext_vector_type(8)))  short bf16x8;
typedef __attribute__((ext_vector_type(16))) float f32x16;
typedef __attribute__((ext_vector_type(2)))  float f32x2;

// pack two f32 -> (bf16(a) | bf16(b)<<16) by truncation: one v_perm_b32
static __device__ __forceinline__ unsigned pktrunc(float a, float b) {
    return __builtin_amdgcn_perm(__float_as_uint(b), __float_as_uint(a), 0x07060302u);
}
// v_permlane32_swap_b32: a.row1 <-> b.row0 (register-only cross-half exchange)
#define PLSWAP(a, b) asm("v_permlane32_swap_b32 %0, %1" : "+v"(a), "+v"(b))

// ---------------- Phase 1: chunk transfer-matrix products ----------------
__global__ __launch_bounds__(256, 4) void crf_chunk(
    const float* __restrict__ feat,   // [B][T][L]
    const float* __restrict__ trans,  // [L][L]
    const int*   __restrict__ lab,    // [B][T]
    float* __restrict__ ws,           // [B*CH][32][32] log-space products
    float* __restrict__ out,          // [1] (gold subtracted here)
    int CHS)
{
    const int CH = 1 << CHS, LEN = TN >> CHS;
    const int l = threadIdx.x & 63, n = l & 31, h = l >> 5;
    const int wid = __builtin_amdgcn_readfirstlane((int)(threadIdx.x >> 6));
    const int gid = blockIdx.x * 4 + wid;            // wave id = chunk id
    const int c = gid & (CH - 1), b = gid >> CHS;

    const float* __restrict__ fb = feat + (size_t)b * TN * LN;
    const int*   __restrict__ lb = lab  + (size_t)b * TN;

    // A-operand constants as pairs: EA for k=8h+2r(+1), EB for k=16+8h+2r(+1)
    f32x2 EA[4], EB[4];
    #pragma unroll
    for (int r = 0; r < 4; ++r) {
        EA[r][0] = __expf(trans[n * LN + 8 * h + 2 * r]          - KSHIFT);
        EA[r][1] = __expf(trans[n * LN + 8 * h + 2 * r + 1]      - KSHIFT);
        EB[r][0] = __expf(trans[n * LN + 16 + 8 * h + 2 * r]     - KSHIFT);
        EB[r][1] = __expf(trans[n * LN + 16 + 8 * h + 2 * r + 1] - KSHIFT);
    }

    // Running product as B operand (lane -> col n, k=8h+e); init Identity.
    union BU { bf16x8 v; unsigned u[4]; } B1f, B2f;
    #pragma unroll
    for (int r = 0; r < 4; ++r) {
        int k0 = 8 * h + 2 * r, k1 = k0 + 1;
        B1f.u[r] = (k0 == n ? 0x3F80u : 0u) | ((k1 == n ? 0x3F80u : 0u) << 16);
        B2f.u[r] = (k0 + 16 == n ? 0x3F80u : 0u) | ((k1 + 16 == n ? 0x3F80u : 0u) << 16);
    }

    const int start = c * LEN, te = start + LEN;
    const int tm = (c == 0) ? 2 : start;   // chunk 0: t=1 folded into alpha_1

    // ---- gold-path prologue (all wave-uniform scalar loads) ----
    float gold = 0.f;
    int pv;
    if (c == 0) {
        int c0 = lb[1];
        gold = trans[c0 * LN + lb[0]] + fb[LN + c0];
        pv = c0;
    } else {
        pv = lb[start - 1];
    }
    int   ct = lb[tm];            // label at t
    int   c1 = lb[tm + 1];        // label at t+1
    float gt = trans[ct * LN + pv];               // gold transition for step tm
    float gf = fb[(size_t)tm * LN + ct];          // gold emission for step tm

    // ---- feature pipeline: 2-deep ----
    float fcur = fb[(size_t)tm * LN + n];
    float f1   = fb[(size_t)(tm + 1) * LN + n];

    int sc = 0;                   // accumulated pow2 exponent (per column)
    f32x16 ZR;
    #pragma unroll
    for (int i = 0; i < 16; ++i) ZR[i] = 0.f;
    f32x16 C;

    for (int t = tm; t < te; ++t) {
        // ---- prefetch t+2 (clamped; dangling values discarded) ----
        const int tp2 = (t + 2 < te) ? (t + 2) : (te - 1);
        const int tp1 = (t + 1 < te) ? (t + 1) : (te - 1);
        float f2 = fb[(size_t)tp2 * LN + n];      // vector load, consumed in 2 iters
        int   c2 = lb[tp2];                       // scalar,   consumed in 2 iters

        // ---- gold for step t (everything prefetched >=1 iter ago) ----
        gold += gt + gf;
        float gtn = trans[c1 * LN + ct];          // for step t+1 (consumed next iter)
        float gfn = fb[(size_t)tp1 * LN + c1];    // for step t+1 (consumed next iter)

        // ---- A = exp(trans + feat_t[row] - K); row factor lane-local ----
        float F = __expf(fcur);
        f32x2 F2; F2[0] = F; F2[1] = F;
        union BU A1, A2;
        #pragma unroll
        for (int r = 0; r < 4; ++r) {
            f32x2 pa = EA[r] * F2;
            f32x2 pb = EB[r] * F2;
            A1.u[r] = pktrunc(pa[0], pa[1]);
            A2.u[r] = pktrunc(pb[0], pb[1]);
        }

        C = __builtin_amdgcn_mfma_f32_32x32x16_bf16(A1.v, B1f.v, ZR, 0, 0, 0);
        C = __builtin_amdgcn_mfma_f32_32x32x16_bf16(A2.v, B2f.v, C, 0, 0, 0);

        // ---- per-column pow2 rescale every 16 steps (exact; diag commutes) ----
        if ((t & 15) == 15) {
            float cm = C[0];
            #pragma unroll
            for (int i = 1; i < 16; ++i) cm = fmaxf(cm, C[i]);
            unsigned ca = __float_as_uint(cm), cb = ca;
            PLSWAP(ca, cb);                       // column consensus across halves
            cm = fmaxf(__uint_as_float(ca), __uint_as_float(cb));
            cm = fmaxf(cm, 1e-30f);
            int ex; frexpf(cm, &ex);
            sc += ex;
            #pragma unroll
            for (int i = 0; i < 16; ++i) C[i] = ldexpf(C[i], -ex);
        }

        // ---- C (col=l&31, row=(r&3)+8*(r>>2)+4h) -> next-step B operands ----
        unsigned PK[8];
        #pragma unroll
        for (int r = 0; r < 8; ++r) PK[r] = pktrunc(C[2 * r], C[2 * r + 1]);
        PLSWAP(PK[0], PK[2]);  PLSWAP(PK[1], PK[3]);
        PLSWAP(PK[4], PK[6]);  PLSWAP(PK[5], PK[7]);
        B1f.u[0] = PK[0]; B1f.u[1] = PK[1]; B1f.u[2] = PK[2]; B1f.u[3] = PK[3];
        B2f.u[0] = PK[4]; B2f.u[1] = PK[5]; B2f.u[2] = PK[6]; B2f.u[3] = PK[7];

        // ---- rotate pipelines ----
        fcur = f1; f1 = f2;
        gt = gtn; gf = gfn;
        ct = c1;  c1 = c2;
    }

    if (l == 0) atomicAdd(out, -gold * (1.0f / (float)BN));

    // write log-space chunk matrix: log(true) = ln(C) + sc*ln2 + K*len
    const float add = KSHIFT * (float)(te - tm) + (float)sc * LN2F;
    float* __restrict__ w = ws + ((size_t)gid << 10);
    #pragma unroll
    for (int r = 0; r < 16; ++r) {
        int row = (r & 3) + 8 * (r >> 2) + 4 * h;
        float v = C[r];
        w[row * LN + n] = (v > 0.f) ? (__logf(v) + add) : -10000.0f;
    }
}

// ---------------- Phase 2: log-space combine + final lse ----------------
__global__ __launch_bounds__(64) void crf_combine(
    const float* __restrict__ trans,
    const float* __restrict__ feat,
    const float* __restrict__ ws,
    float* __restrict__ out,
    int CHS)
{
    const int CH = 1 << CHS;
    const int l = threadIdx.x & 63, i = l & 31;
    const int seq = blockIdx.x * 2 + (l >> 5);
    const int bb = (l & 32) << 2;   // group-local bpermute base

    // alpha_1[i] = trans[i][0] + feat[1][i]  (exact)
    float alpha = trans[i * LN] + feat[(size_t)seq * TN * LN + LN + i];
    const float* __restrict__ wsb = ws + ((size_t)seq << (10 + CHS));

    for (int c = 0; c < CH; ++c) {
        const float4* Mr = (const float4*)(wsb + (c << 10) + i * LN);
        float vv[32];
        #pragma unroll
        for (int q = 0; q < 8; ++q) {
            float4 m4 = Mr[q];
            vv[4 * q + 0] = m4.x; vv[4 * q + 1] = m4.y;
            vv[4 * q + 2] = m4.z; vv[4 * q + 3] = m4.w;
        }
        float mx = -1e30f;
        #pragma unroll
        for (int j = 0; j < 32; ++j) {
            int r = __builtin_amdgcn_ds_bpermute(bb + (j << 2), __float_as_int(alpha));
            vv[j] += __int_as_float(r);
            mx = fmaxf(mx, vv[j]);
        }
        float s = 0.f;
        #pragma unroll
        for (int j = 0; j < 32; ++j) s += __expf(vv[j] - mx);
        alpha = mx + __logf(s);
    }

    // forward score = lse over 32 states
    float m = alpha;
    #pragma unroll
    for (int s = 16; s; s >>= 1) m = fmaxf(m, __shfl_xor(m, s, 32));
    float es = __expf(alpha - m);
    #pragma unroll
    for (int s = 16; s; s >>= 1) es += __shfl_xor(es, s, 32);
    float fs = m + __logf(es);

    if (i == 0) atomicAdd(out, fs * (1.0f / (float)BN));
}

extern "C" void kernel_launch(void* const* d_in, const int* in_sizes, int n_in,
                              void* d_out, int out_size, void* d_ws, size_t ws_size,
                              hipStream_t stream) {
    const float* features    = (const float*)d_in[0];
    const float* transitions = (const float*)d_in[1];
    const int*   labels      = (const int*)d_in[2];
    float* out = (float*)d_out;
    float* ws  = (float*)d_ws;

    int CHS = 3;
    while (CHS > 0 && ws_size < (((size_t)BN << CHS) * (LN * LN * 4))) --CHS;
    const int CH = 1 << CHS;

    hipMemsetAsync(out, 0, sizeof(float), stream);
    crf_chunk<<<dim3((BN * CH) / 4), dim3(256), 0, stream>>>(
        features, transitions, labels, ws, out, CHS);
    crf_combine<<<dim3(BN / 2), dim3(64), 0, stream>>>(
        transitions, features, ws, out, CHS);
}